// Round 13
// baseline (628.615 us; speedup 1.0000x reference)
//
#include <hip/hip_runtime.h>
#include <stdint.h>

typedef unsigned short u16;
typedef unsigned int u32;
typedef float f32x4 __attribute__((ext_vector_type(4)));
typedef __bf16 bf16x8 __attribute__((ext_vector_type(8)));
typedef u16 u16x8 __attribute__((ext_vector_type(8)));
typedef u16 u16x4 __attribute__((ext_vector_type(4)));

// Problem geometry (fixed)
#define NB   4
#define SEQ  2048
#define EMB  1024
#define NH   16
#define HDIM 64

#define QSCALE 0.18033688011112042f   // log2(e)/8, folded into qp at projection

__device__ __forceinline__ f32x4 mfma16(bf16x8 a, bf16x8 b, f32x4 c) {
  return __builtin_amdgcn_mfma_f32_16x16x32_bf16(a, b, c, 0, 0, 0);
}
__device__ __forceinline__ u16 f2bf(float f) {
  u32 u = __builtin_bit_cast(u32, f);
  u += 0x7FFFu + ((u >> 16) & 1u);      // round-to-nearest-even
  return (u16)(u >> 16);
}
__device__ __forceinline__ u32 pk2bf(float lo, float hi) {
  return (u32)f2bf(lo) | ((u32)f2bf(hi) << 16);
}
__device__ __forceinline__ float bf2f(u16 h) {
  return __builtin_bit_cast(float, (u32)h << 16);
}
__device__ __forceinline__ bf16x8 ldg8(const u16* p) {
  return *reinterpret_cast<const bf16x8*>(p);
}

// ---------------- prep: fp32->bf16 cvt (y=0..5) + mask bitpack (y=6) ----------------
__global__ __launch_bounds__(256) void prep_kernel(
    const float* __restrict__ q, const float* __restrict__ k, const float* __restrict__ v,
    const float* __restrict__ Wk, const float* __restrict__ Wv, const float* __restrict__ Wo,
    const int* __restrict__ mask,
    u16* __restrict__ qb, u16* __restrict__ kb, u16* __restrict__ vb,
    u16* __restrict__ Wkb, u16* __restrict__ Wvb, u16* __restrict__ Wob,
    u32* __restrict__ bits) {
  const int y = blockIdx.y;
  if (y == 6) {
    const int idx = blockIdx.x * 256 + threadIdx.x;
    if (idx >= NB * SEQ * 64) return;
    const int w = idx & 63;
    const size_t rowbase = (size_t)(idx >> 6) * SEQ;
    const int4* p = reinterpret_cast<const int4*>(mask + rowbase + w * 32);
    u32 m = 0;
#pragma unroll
    for (int j = 0; j < 8; ++j) {
      int4 v4 = p[j];
      m |= (v4.x != 0 ? 1u : 0u) << (j * 4 + 0);
      m |= (v4.y != 0 ? 1u : 0u) << (j * 4 + 1);
      m |= (v4.z != 0 ? 1u : 0u) << (j * 4 + 2);
      m |= (v4.w != 0 ? 1u : 0u) << (j * 4 + 3);
    }
    bits[idx] = m;
    return;
  }
  const float* src; u16* dst; int n8;
  switch (y) {
    case 0: src = q;  dst = qb;  n8 = NB * SEQ * EMB / 8; break;
    case 1: src = k;  dst = kb;  n8 = NB * SEQ * EMB / 8; break;
    case 2: src = v;  dst = vb;  n8 = NB * SEQ * EMB / 8; break;
    case 3: src = Wk; dst = Wkb; n8 = EMB * EMB / 8; break;
    case 4: src = Wv; dst = Wvb; n8 = EMB * EMB / 8; break;
    default: src = Wo; dst = Wob; n8 = EMB * EMB / 8; break;
  }
  int i = blockIdx.x * 256 + threadIdx.x;
  if (i >= n8) return;
  const float4* s = reinterpret_cast<const float4*>(src) + (size_t)i * 2;
  float4 a = s[0], b = s[1];
  u16x8 o;
  o[0] = f2bf(a.x); o[1] = f2bf(a.y); o[2] = f2bf(a.z); o[3] = f2bf(a.w);
  o[4] = f2bf(b.x); o[5] = f2bf(b.y); o[6] = f2bf(b.z); o[7] = f2bf(b.w);
  reinterpret_cast<u16x8*>(dst)[i] = o;
}

// per (b, 64-row qtile, 64-col ktile): 1 if fully unmasked
__global__ __launch_bounds__(256) void tileok_kernel(const u32* __restrict__ bits,
                                                     unsigned char* __restrict__ tok) {
  const int idx = blockIdx.x * 256 + threadIdx.x;      // < 4*32*32
  const int b = idx >> 10, qt = (idx >> 5) & 31, kt = idx & 31;
  const u32* bb = bits + (size_t)b * SEQ * 64;
  u32 acc = 0xFFFFFFFFu;
  for (int rr = 0; rr < 64; ++rr) {
    const u32* pr = bb + (size_t)(qt * 64 + rr) * 64 + kt * 2;
    acc &= pr[0] & pr[1];
  }
  tok[idx] = (acc == 0xFFFFFFFFu) ? 1 : 0;
}

// ---------------- 128x128x(K=1024) bf16 GEMM mainloop (m97 structure) ----------------
__device__ __forceinline__ void gemm_tile(const u16* __restrict__ A,
                                          const u16* __restrict__ W,
                                          int brow, int bcol, int tid,
                                          u16* As, u16* Bs, f32x4 acc[4][4]) {
  const int K = 1024;
  const int l = tid & 63, wv = tid >> 6;
  const int lr = l & 15, lg = l >> 4;
  const int wr = wv >> 1, wc = wv & 1;
  const int srow = l >> 3;
  const int skb = (l & 7) * 16;

  for (int k0 = 0; k0 < K; k0 += 64) {
#pragma unroll
    for (int r = 0; r < 4; ++r) {
      const int chunk = r * 4 + wv;
      const int row = chunk * 8 + srow;
      const char* ga = (const char*)A + ((size_t)(brow + row) * K + k0) * 2 + skb;
      const char* gb = (const char*)W + ((size_t)(bcol + row) * K + k0) * 2 + skb;
      __builtin_amdgcn_global_load_lds(
          (const __attribute__((address_space(1))) u32*)ga,
          (__attribute__((address_space(3))) u32*)((char*)As + chunk * 1024), 16, 0, 0);
      __builtin_amdgcn_global_load_lds(
          (const __attribute__((address_space(1))) u32*)gb,
          (__attribute__((address_space(3))) u32*)((char*)Bs + chunk * 1024), 16, 0, 0);
    }
    __syncthreads();
#pragma unroll
    for (int ks = 0; ks < 2; ++ks) {
      bf16x8 af[4], bfr[4];
#pragma unroll
      for (int m = 0; m < 4; ++m)
        af[m] = *reinterpret_cast<const bf16x8*>(
            (const char*)As + (wr * 64 + m * 16 + lr) * 128 + ks * 64 + lg * 16);
#pragma unroll
      for (int n = 0; n < 4; ++n)
        bfr[n] = *reinterpret_cast<const bf16x8*>(
            (const char*)Bs + (wc * 64 + n * 16 + lr) * 128 + ks * 64 + lg * 16);
#pragma unroll
      for (int m = 0; m < 4; ++m)
#pragma unroll
        for (int n = 0; n < 4; ++n)
          acc[m][n] = mfma16(af[m], bfr[n], acc[m][n]);
    }
    __syncthreads();
  }
}

// z=0: qp = (q@Wv^T+bv)*QSCALE  [B][H][S][HD]
// z=1: kp = k@Wk^T+bk           [B][H][S][HD]
// z=2: vpT = v@Wv^T+bv          [B][H][HD][S] (transposed via LDS)
__global__ __launch_bounds__(256) void proj_gemm(
    const u16* __restrict__ qb, const u16* __restrict__ kb, const u16* __restrict__ vb,
    const u16* __restrict__ Wvb, const u16* __restrict__ Wkb,
    const float* __restrict__ bv, const float* __restrict__ bkp,
    u16* __restrict__ qp, u16* __restrict__ kp, u16* __restrict__ vpT) {
  __shared__ __align__(16) u32 smem_u32[8192];
  u16* As = (u16*)smem_u32;
  u16* Bs = As + 128 * 64;
  const int z = blockIdx.z;
  const u16* A = (z == 0) ? qb : (z == 1) ? kb : vb;
  const u16* W = (z == 1) ? Wkb : Wvb;
  const float* bias = (z == 1) ? bkp : bv;
  const int brow = blockIdx.y * 128;
  const int bcol = blockIdx.x * 128;
  const int tid = threadIdx.x;
  f32x4 acc[4][4] = {};
  gemm_tile(A, W, brow, bcol, tid, As, Bs, acc);
  const int l = tid & 63, wv = tid >> 6;
  const int lr = l & 15, lg = l >> 4;
  const int wr = wv >> 1, wc = wv & 1;

  if (z == 2) {
#pragma unroll
    for (int m = 0; m < 4; ++m)
#pragma unroll
      for (int n = 0; n < 4; ++n) {
        const int cl = wc * 64 + n * 16 + lr;
        const float b0 = bias[bcol + cl];
        const u32 w0 = pk2bf(acc[m][n][0] + b0, acc[m][n][1] + b0);
        const u32 w1 = pk2bf(acc[m][n][2] + b0, acc[m][n][3] + b0);
        const int rp0 = wr * 32 + m * 8 + lg * 2;
        const int a32 = cl * 64 + (rp0 ^ ((lr & 7) << 2));
        uint2 wv2; wv2.x = w0; wv2.y = w1;
        *reinterpret_cast<uint2*>(&smem_u32[a32]) = wv2;
      }
    __syncthreads();
#pragma unroll
    for (int i = 0; i < 8; ++i) {
      const int idx = i * 256 + tid;
      const int cl = idx >> 4;
      const int rp0 = (idx & 15) * 4;
      const int a32 = cl * 64 + (rp0 ^ ((cl & 7) << 2));
      const uint4 d = *reinterpret_cast<const uint4*>(&smem_u32[a32]);
      const int col = bcol + cl, hh = col >> 6, hd = col & 63;
      const int row = brow + rp0 * 2, bb = row >> 11, s = row & 2047;
      *reinterpret_cast<uint4*>(
          vpT + ((((size_t)bb * NH + hh) * HDIM + hd) * SEQ + s)) = d;
    }
  } else {
    u16* dst = (z == 0) ? qp : kp;
    const float sc = (z == 0) ? QSCALE : 1.0f;
#pragma unroll
    for (int m = 0; m < 4; ++m)
#pragma unroll
      for (int n = 0; n < 4; ++n)
#pragma unroll
        for (int r = 0; r < 4; ++r) {
          const int row = brow + wr * 64 + m * 16 + lg * 4 + r;
          const int col = bcol + wc * 64 + n * 16 + lr;
          const float vl = (acc[m][n][r] + bias[col]) * sc;
          const int bb = row >> 11, s = row & 2047, hh = col >> 6, hd = col & 63;
          dst[(((size_t)bb * NH + hh) * SEQ + s) * HDIM + hd] = f2bf(vl);
        }
  }
}

__global__ __launch_bounds__(256) void out_gemm(
    const u16* __restrict__ ctxb, const u16* __restrict__ Wob,
    const float* __restrict__ bo, float* __restrict__ outF) {
  __shared__ __align__(16) u32 smem_u32[8192];
  u16* As = (u16*)smem_u32;
  u16* Bs = As + 128 * 64;
  const int brow = blockIdx.y * 128;
  const int bcol = blockIdx.x * 128;
  const int tid = threadIdx.x;
  f32x4 acc[4][4] = {};
  gemm_tile(ctxb, Wob, brow, bcol, tid, As, Bs, acc);
  const int l = tid & 63, wv = tid >> 6;
  const int lr = l & 15, lg = l >> 4;
  const int wr = wv >> 1, wc = wv & 1;
#pragma unroll
  for (int m = 0; m < 4; ++m)
#pragma unroll
    for (int n = 0; n < 4; ++n)
#pragma unroll
      for (int r = 0; r < 4; ++r) {
        const int row = brow + wr * 64 + m * 16 + lg * 4 + r;
        const int col = bcol + wc * 64 + n * 16 + lr;
        outF[(size_t)row * EMB + col] = acc[m][n][r] + bo[col];
      }
}

// ---------------- fused attention: block-level K/V LDS staging, 128 q-rows/block ----------------
// 1024 blocks = 64 bh x 16 qg (bh = bid&63 -> XCD = bh%8). 4 waves; wave owns
// 32 q-rows (q0w = qg*128 + wid*32) -> rowsums/ctx stay WAVE-PRIVATE (R10 path).
// Per kt-tile all waves cooperatively stage K (pass1) / K+V (pass2) into LDS via
// global_load_lds with PRE-SWIZZLED global source (cs ^= row&7 on 16B granules;
// linear LDS dest), consumed by ds_read_b128 with the same XOR -> balanced banks.
// K/V logical global reads: 3.1 GB -> 0.79 GB (the measured ~8 TB/s read ceiling
// is per-CU L1-miss concurrency; only volume cuts help).
// attn stores are PLAIN f32x4 (barrier vmcnt-drain waits only for L2 ack).
// LDS 32.25 KB -> 4 blocks/CU.
__global__ __launch_bounds__(256) void attn_kernel(
    const u16* __restrict__ qp, const u16* __restrict__ kp, const u16* __restrict__ vpT,
    const u32* __restrict__ bits, const unsigned char* __restrict__ tok,
    float* __restrict__ attn, u16* __restrict__ ctxb) {
  __shared__ __align__(16) u16 Ks[4096];               // 8 KB: [row64][cs8^][8elem]
  __shared__ __align__(16) u16 Vs[4096];               // 8 KB
  __shared__ __align__(16) u16 pbuf[4][32][64];        // 16 KB, wave-private
  const int tid = threadIdx.x;
  const int l = tid & 63, wid = tid >> 6;
  const int lr = l & 15, lg = l >> 4;
  const int bid = blockIdx.x;
  const int bh_i = bid & 63;                           // XCD = bh%8
  const int qg = bid >> 6;                             // 0..15
  const int h = bh_i & 15, b = bh_i >> 4;
  const int q0w = qg * 128 + wid * 32;                 // this wave's 32 rows
  const size_t bh = (size_t)b * NH + h;
  const u16* qpb = qp + bh * (SEQ * HDIM);
  const u16* kpb = kp + bh * (SEQ * HDIM);
  const u16* vpb = vpT + bh * (HDIM * SEQ);
  float* attb = attn + bh * ((size_t)SEQ * SEQ);
  const unsigned char* tokb = tok + ((size_t)b * 32 + (q0w >> 6)) * 32;
  const u32* bitsb = bits + (size_t)b * SEQ * 64;

  // Q fragments: rows q0w + g*16 + lr, k-dim d*32 + lg*8
  bf16x8 aq[2][2];
#pragma unroll
  for (int g = 0; g < 2; ++g)
#pragma unroll
    for (int d = 0; d < 2; ++d)
      aq[g][d] = ldg8(qpb + (size_t)(q0w + g * 16 + lr) * HDIM + d * 32 + lg * 8);

  // ---- pass 1: rowsums (K staged in LDS per tile) ----
  float sums[2][4] = {{0.f, 0.f, 0.f, 0.f}, {0.f, 0.f, 0.f, 0.f}};
  for (int kt = 0; kt < 32; ++kt) {
    const int kc = kt * 64;
#pragma unroll
    for (int c = 0; c < 2; ++c) {
      const int gi = c * 256 + tid;
      const int row = gi >> 3, cs = gi & 7;
      const int csx = cs ^ (row & 7);
      __builtin_amdgcn_global_load_lds(
          (const __attribute__((address_space(1))) u32*)
              ((const char*)(kpb + (size_t)(kc + row) * HDIM) + csx * 16),
          (__attribute__((address_space(3))) u32*)((char*)Ks + c * 4096 + wid * 1024),
          16, 0, 0);
    }
    __syncthreads();
    const bool okt = tokb[kt] != 0;
    bf16x8 bk8[4][2];
#pragma unroll
    for (int st = 0; st < 4; ++st)
#pragma unroll
      for (int d = 0; d < 2; ++d) {
        const int row = st * 16 + lr;
        bk8[st][d] = *reinterpret_cast<const bf16x8*>(
            Ks + (((row << 3) | ((d * 4 + lg) ^ (row & 7))) << 3));
      }
#pragma unroll
    for (int g = 0; g < 2; ++g)
#pragma unroll
      for (int st = 0; st < 4; ++st) {
        f32x4 s = {0.f, 0.f, 0.f, 0.f};
        s = mfma16(aq[g][0], bk8[st][0], s);
        s = mfma16(aq[g][1], bk8[st][1], s);
#pragma unroll
        for (int r = 0; r < 4; ++r) {
          float sc = s[r];
          if (!okt) {
            const int qrow = q0w + g * 16 + lg * 4 + r;
            const int kpos = kc + st * 16 + lr;
            const u32 wb = bitsb[(size_t)qrow * 64 + (kpos >> 5)];
            if (!((wb >> (kpos & 31)) & 1u)) sc = -1e30f;
          }
          sums[g][r] += __builtin_amdgcn_exp2f(sc);
        }
      }
    __syncthreads();
  }
  float rinv[2][4];
#pragma unroll
  for (int g = 0; g < 2; ++g)
#pragma unroll
    for (int r = 0; r < 4; ++r) {
      float vsum = sums[g][r];
      vsum += __shfl_xor(vsum, 1);
      vsum += __shfl_xor(vsum, 2);
      vsum += __shfl_xor(vsum, 4);
      vsum += __shfl_xor(vsum, 8);
      rinv[g][r] = 1.0f / vsum;
    }

  // ---- pass 2: K+V staged; scores -> pbuf -> PV -> plain f32x4 stores ----
  f32x4 cacc[2][4] = {};
  for (int kt = 0; kt < 32; ++kt) {
    const int kc = kt * 64;
#pragma unroll
    for (int c = 0; c < 2; ++c) {
      const int gi = c * 256 + tid;
      const int row = gi >> 3, cs = gi & 7;
      const int csx = cs ^ (row & 7);
      __builtin_amdgcn_global_load_lds(
          (const __attribute__((address_space(1))) u32*)
              ((const char*)(kpb + (size_t)(kc + row) * HDIM) + csx * 16),
          (__attribute__((address_space(3))) u32*)((char*)Ks + c * 4096 + wid * 1024),
          16, 0, 0);
      __builtin_amdgcn_global_load_lds(
          (const __attribute__((address_space(1))) u32*)
              ((const char*)(vpb + (size_t)row * SEQ + kc) + csx * 16),
          (__attribute__((address_space(3))) u32*)((char*)Vs + c * 4096 + wid * 1024),
          16, 0, 0);
    }
    __syncthreads();
    const bool okt = tokb[kt] != 0;
    bf16x8 bk8[4][2];
#pragma unroll
    for (int st = 0; st < 4; ++st)
#pragma unroll
      for (int d = 0; d < 2; ++d) {
        const int row = st * 16 + lr;
        bk8[st][d] = *reinterpret_cast<const bf16x8*>(
            Ks + (((row << 3) | ((d * 4 + lg) ^ (row & 7))) << 3));
      }
#pragma unroll
    for (int g = 0; g < 2; ++g)
#pragma unroll
      for (int st = 0; st < 4; ++st) {
        f32x4 s = {0.f, 0.f, 0.f, 0.f};
        s = mfma16(aq[g][0], bk8[st][0], s);
        s = mfma16(aq[g][1], bk8[st][1], s);
#pragma unroll
        for (int r = 0; r < 4; ++r) {
          float sc = s[r];
          if (!okt) {
            const int qrow = q0w + g * 16 + lg * 4 + r;
            const int kpos = kc + st * 16 + lr;
            const u32 wb = bitsb[(size_t)qrow * 64 + (kpos >> 5)];
            if (!((wb >> (kpos & 31)) & 1u)) sc = -1e30f;
          }
          const float pn = __builtin_amdgcn_exp2f(sc) * rinv[g][r];
          const int row = g * 16 + lg * 4 + r;
          const int col = st * 16 + lr;
          pbuf[wid][row][col ^ ((row & 7) << 3)] = f2bf(pn);
        }
      }
    // V fragments from LDS
    bf16x8 vf[4][2];
#pragma unroll
    for (int ds = 0; ds < 4; ++ds)
#pragma unroll
      for (int x = 0; x < 2; ++x) {
        const int row = ds * 16 + lr;
        vf[ds][x] = *reinterpret_cast<const bf16x8*>(
            Vs + (((row << 3) | ((x * 4 + lg) ^ (row & 7))) << 3));
      }
    // PV: wave-local pbuf readback as A-fragments
#pragma unroll
    for (int g = 0; g < 2; ++g)
#pragma unroll
      for (int ks = 0; ks < 2; ++ks) {
        const int prow = g * 16 + lr;
        const int cb = ks * 32 + lg * 8;
        const bf16x8 pa = *reinterpret_cast<const bf16x8*>(
            &pbuf[wid][prow][cb ^ ((prow & 7) << 3)]);
#pragma unroll
        for (int ds = 0; ds < 4; ++ds)
          cacc[g][ds] = mfma16(pa, vf[ds][ks], cacc[g][ds]);
      }
    // plain vectorized attn stores: 8 instrs x 1KB; rows i*4+lg, cols (l&15)*4
#pragma unroll
    for (int i = 0; i < 8; ++i) {
      const int row = i * 4 + lg;
      const int c4 = (l & 15) * 4;
      const u16x4 raw = *reinterpret_cast<const u16x4*>(
          &pbuf[wid][row][c4 ^ ((row & 7) << 3)]);
      f32x4 o;
      o[0] = bf2f(raw[0]); o[1] = bf2f(raw[1]);
      o[2] = bf2f(raw[2]); o[3] = bf2f(raw[3]);
      *reinterpret_cast<f32x4*>(attb + (size_t)(q0w + row) * SEQ + kc + c4) = o;
    }
    __syncthreads();
  }

  // ctx write: rows q0w + g*16 + lg*4 + r, d-col ds*16+lr (wave-private)
#pragma unroll
  for (int g = 0; g < 2; ++g)
#pragma unroll
    for (int ds = 0; ds < 4; ++ds)
#pragma unroll
      for (int r = 0; r < 4; ++r)
        ctxb[((size_t)b * SEQ + q0w + g * 16 + lg * 4 + r) * EMB + h * HDIM + ds * 16 + lr] =
            f2bf(cacc[g][ds][r]);
}

// ---------------- host launch ----------------
extern "C" void kernel_launch(void* const* d_in, const int* in_sizes, int n_in,
                              void* d_out, int out_size, void* d_ws, size_t ws_size,
                              hipStream_t stream) {
  const float* q   = (const float*)d_in[0];
  const float* k   = (const float*)d_in[1];
  const float* v   = (const float*)d_in[2];
  const int* mask  = (const int*)d_in[3];
  const float* Wk  = (const float*)d_in[4];
  const float* bk  = (const float*)d_in[5];
  const float* Wv  = (const float*)d_in[6];
  const float* bv  = (const float*)d_in[7];
  const float* Wo  = (const float*)d_in[8];
  const float* bo  = (const float*)d_in[9];

  float* outF = (float*)d_out;
  float* attnF = outF + (size_t)NB * SEQ * EMB;

  const size_t MiB = 1024 * 1024;
  char* ws = (char*)d_ws;
  u16* qb   = (u16*)(ws + 0 * MiB);
  u16* kb   = (u16*)(ws + 16 * MiB);
  u16* vb   = (u16*)(ws + 32 * MiB);
  u16* Wvb  = (u16*)(ws + 48 * MiB);
  u16* Wkb  = (u16*)(ws + 50 * MiB);
  u16* Wob  = (u16*)(ws + 52 * MiB);
  u16* qpB  = (u16*)(ws + 54 * MiB);
  u16* kpB  = (u16*)(ws + 70 * MiB);
  u16* vpT  = (u16*)(ws + 86 * MiB);
  u16* ctxb = (u16*)(ws + 102 * MiB);
  u32* bits = (u32*)(ws + 118 * MiB);
  unsigned char* tok = (unsigned char*)(ws + 120 * MiB);

  prep_kernel<<<dim3(NB * SEQ * EMB / 8 / 256, 7), 256, 0, stream>>>(
      q, k, v, Wk, Wv, Wo, mask, qb, kb, vb, Wkb, Wvb, Wob, bits);

  tileok_kernel<<<NB * 32 * 32 / 256, 256, 0, stream>>>(bits, tok);

  proj_gemm<<<dim3(EMB / 128, NB * SEQ / 128, 3), 256, 0, stream>>>(
      qb, kb, vb, Wvb, Wkb, bv, bk, qpB, kpB, vpT);

  attn_kernel<<<1024, 256, 0, stream>>>(
      qpB, kpB, vpT, bits, tok, attnF, ctxb);

  out_gemm<<<dim3(EMB / 128, NB * SEQ / 128), 256, 0, stream>>>(ctxb, Wob, bo, outF);
}

// Round 14
// 591.724 us; speedup vs baseline: 1.0623x; 1.0623x over previous
//
#include <hip/hip_runtime.h>
#include <stdint.h>

typedef unsigned short u16;
typedef unsigned int u32;
typedef float f32x4 __attribute__((ext_vector_type(4)));
typedef __bf16 bf16x8 __attribute__((ext_vector_type(8)));
typedef u16 u16x8 __attribute__((ext_vector_type(8)));
typedef u16 u16x4 __attribute__((ext_vector_type(4)));

// Problem geometry (fixed)
#define NB   4
#define SEQ  2048
#define EMB  1024
#define NH   16
#define HDIM 64

#define QSCALE 0.18033688011112042f   // log2(e)/8, folded into qp at projection

__device__ __forceinline__ f32x4 mfma16(bf16x8 a, bf16x8 b, f32x4 c) {
  return __builtin_amdgcn_mfma_f32_16x16x32_bf16(a, b, c, 0, 0, 0);
}
__device__ __forceinline__ u16 f2bf(float f) {
  u32 u = __builtin_bit_cast(u32, f);
  u += 0x7FFFu + ((u >> 16) & 1u);      // round-to-nearest-even
  return (u16)(u >> 16);
}
__device__ __forceinline__ u32 pk2bf(float lo, float hi) {
  return (u32)f2bf(lo) | ((u32)f2bf(hi) << 16);
}
__device__ __forceinline__ float bf2f(u16 h) {
  return __builtin_bit_cast(float, (u32)h << 16);
}
__device__ __forceinline__ bf16x8 ldg8(const u16* p) {
  return *reinterpret_cast<const bf16x8*>(p);
}

// ---------------- prep: fp32->bf16 cvt (y=0..5) + mask bitpack (y=6) ----------------
__global__ __launch_bounds__(256) void prep_kernel(
    const float* __restrict__ q, const float* __restrict__ k, const float* __restrict__ v,
    const float* __restrict__ Wk, const float* __restrict__ Wv, const float* __restrict__ Wo,
    const int* __restrict__ mask,
    u16* __restrict__ qb, u16* __restrict__ kb, u16* __restrict__ vb,
    u16* __restrict__ Wkb, u16* __restrict__ Wvb, u16* __restrict__ Wob,
    u32* __restrict__ bits) {
  const int y = blockIdx.y;
  if (y == 6) {
    const int idx = blockIdx.x * 256 + threadIdx.x;
    if (idx >= NB * SEQ * 64) return;
    const int w = idx & 63;
    const size_t rowbase = (size_t)(idx >> 6) * SEQ;
    const int4* p = reinterpret_cast<const int4*>(mask + rowbase + w * 32);
    u32 m = 0;
#pragma unroll
    for (int j = 0; j < 8; ++j) {
      int4 v4 = p[j];
      m |= (v4.x != 0 ? 1u : 0u) << (j * 4 + 0);
      m |= (v4.y != 0 ? 1u : 0u) << (j * 4 + 1);
      m |= (v4.z != 0 ? 1u : 0u) << (j * 4 + 2);
      m |= (v4.w != 0 ? 1u : 0u) << (j * 4 + 3);
    }
    bits[idx] = m;
    return;
  }
  const float* src; u16* dst; int n8;
  switch (y) {
    case 0: src = q;  dst = qb;  n8 = NB * SEQ * EMB / 8; break;
    case 1: src = k;  dst = kb;  n8 = NB * SEQ * EMB / 8; break;
    case 2: src = v;  dst = vb;  n8 = NB * SEQ * EMB / 8; break;
    case 3: src = Wk; dst = Wkb; n8 = EMB * EMB / 8; break;
    case 4: src = Wv; dst = Wvb; n8 = EMB * EMB / 8; break;
    default: src = Wo; dst = Wob; n8 = EMB * EMB / 8; break;
  }
  int i = blockIdx.x * 256 + threadIdx.x;
  if (i >= n8) return;
  const float4* s = reinterpret_cast<const float4*>(src) + (size_t)i * 2;
  float4 a = s[0], b = s[1];
  u16x8 o;
  o[0] = f2bf(a.x); o[1] = f2bf(a.y); o[2] = f2bf(a.z); o[3] = f2bf(a.w);
  o[4] = f2bf(b.x); o[5] = f2bf(b.y); o[6] = f2bf(b.z); o[7] = f2bf(b.w);
  reinterpret_cast<u16x8*>(dst)[i] = o;
}

// per (b, 64-row qtile, 64-col ktile): 1 if fully unmasked
__global__ __launch_bounds__(256) void tileok_kernel(const u32* __restrict__ bits,
                                                     unsigned char* __restrict__ tok) {
  const int idx = blockIdx.x * 256 + threadIdx.x;      // < 4*32*32
  const int b = idx >> 10, qt = (idx >> 5) & 31, kt = idx & 31;
  const u32* bb = bits + (size_t)b * SEQ * 64;
  u32 acc = 0xFFFFFFFFu;
  for (int rr = 0; rr < 64; ++rr) {
    const u32* pr = bb + (size_t)(qt * 64 + rr) * 64 + kt * 2;
    acc &= pr[0] & pr[1];
  }
  tok[idx] = (acc == 0xFFFFFFFFu) ? 1 : 0;
}

// ---------------- 128x128x(K=1024) bf16 GEMM mainloop (m97 structure) ----------------
__device__ __forceinline__ void gemm_tile(const u16* __restrict__ A,
                                          const u16* __restrict__ W,
                                          int brow, int bcol, int tid,
                                          u16* As, u16* Bs, f32x4 acc[4][4]) {
  const int K = 1024;
  const int l = tid & 63, wv = tid >> 6;
  const int lr = l & 15, lg = l >> 4;
  const int wr = wv >> 1, wc = wv & 1;
  const int srow = l >> 3;
  const int skb = (l & 7) * 16;

  for (int k0 = 0; k0 < K; k0 += 64) {
#pragma unroll
    for (int r = 0; r < 4; ++r) {
      const int chunk = r * 4 + wv;
      const int row = chunk * 8 + srow;
      const char* ga = (const char*)A + ((size_t)(brow + row) * K + k0) * 2 + skb;
      const char* gb = (const char*)W + ((size_t)(bcol + row) * K + k0) * 2 + skb;
      __builtin_amdgcn_global_load_lds(
          (const __attribute__((address_space(1))) u32*)ga,
          (__attribute__((address_space(3))) u32*)((char*)As + chunk * 1024), 16, 0, 0);
      __builtin_amdgcn_global_load_lds(
          (const __attribute__((address_space(1))) u32*)gb,
          (__attribute__((address_space(3))) u32*)((char*)Bs + chunk * 1024), 16, 0, 0);
    }
    __syncthreads();
#pragma unroll
    for (int ks = 0; ks < 2; ++ks) {
      bf16x8 af[4], bfr[4];
#pragma unroll
      for (int m = 0; m < 4; ++m)
        af[m] = *reinterpret_cast<const bf16x8*>(
            (const char*)As + (wr * 64 + m * 16 + lr) * 128 + ks * 64 + lg * 16);
#pragma unroll
      for (int n = 0; n < 4; ++n)
        bfr[n] = *reinterpret_cast<const bf16x8*>(
            (const char*)Bs + (wc * 64 + n * 16 + lr) * 128 + ks * 64 + lg * 16);
#pragma unroll
      for (int m = 0; m < 4; ++m)
#pragma unroll
        for (int n = 0; n < 4; ++n)
          acc[m][n] = mfma16(af[m], bfr[n], acc[m][n]);
    }
    __syncthreads();
  }
}

// z=0: qp = (q@Wv^T+bv)*QSCALE  [B][H][S][HD]
// z=1: kp = k@Wk^T+bk           [B][H][S][HD]
// z=2: vpT = v@Wv^T+bv          [B][H][HD][S] (transposed via LDS)
__global__ __launch_bounds__(256) void proj_gemm(
    const u16* __restrict__ qb, const u16* __restrict__ kb, const u16* __restrict__ vb,
    const u16* __restrict__ Wvb, const u16* __restrict__ Wkb,
    const float* __restrict__ bv, const float* __restrict__ bkp,
    u16* __restrict__ qp, u16* __restrict__ kp, u16* __restrict__ vpT) {
  __shared__ __align__(16) u32 smem_u32[8192];
  u16* As = (u16*)smem_u32;
  u16* Bs = As + 128 * 64;
  const int z = blockIdx.z;
  const u16* A = (z == 0) ? qb : (z == 1) ? kb : vb;
  const u16* W = (z == 1) ? Wkb : Wvb;
  const float* bias = (z == 1) ? bkp : bv;
  const int brow = blockIdx.y * 128;
  const int bcol = blockIdx.x * 128;
  const int tid = threadIdx.x;
  f32x4 acc[4][4] = {};
  gemm_tile(A, W, brow, bcol, tid, As, Bs, acc);
  const int l = tid & 63, wv = tid >> 6;
  const int lr = l & 15, lg = l >> 4;
  const int wr = wv >> 1, wc = wv & 1;

  if (z == 2) {
#pragma unroll
    for (int m = 0; m < 4; ++m)
#pragma unroll
      for (int n = 0; n < 4; ++n) {
        const int cl = wc * 64 + n * 16 + lr;
        const float b0 = bias[bcol + cl];
        const u32 w0 = pk2bf(acc[m][n][0] + b0, acc[m][n][1] + b0);
        const u32 w1 = pk2bf(acc[m][n][2] + b0, acc[m][n][3] + b0);
        const int rp0 = wr * 32 + m * 8 + lg * 2;
        const int a32 = cl * 64 + (rp0 ^ ((lr & 7) << 2));
        uint2 wv2; wv2.x = w0; wv2.y = w1;
        *reinterpret_cast<uint2*>(&smem_u32[a32]) = wv2;
      }
    __syncthreads();
#pragma unroll
    for (int i = 0; i < 8; ++i) {
      const int idx = i * 256 + tid;
      const int cl = idx >> 4;
      const int rp0 = (idx & 15) * 4;
      const int a32 = cl * 64 + (rp0 ^ ((cl & 7) << 2));
      const uint4 d = *reinterpret_cast<const uint4*>(&smem_u32[a32]);
      const int col = bcol + cl, hh = col >> 6, hd = col & 63;
      const int row = brow + rp0 * 2, bb = row >> 11, s = row & 2047;
      *reinterpret_cast<uint4*>(
          vpT + ((((size_t)bb * NH + hh) * HDIM + hd) * SEQ + s)) = d;
    }
  } else {
    u16* dst = (z == 0) ? qp : kp;
    const float sc = (z == 0) ? QSCALE : 1.0f;
#pragma unroll
    for (int m = 0; m < 4; ++m)
#pragma unroll
      for (int n = 0; n < 4; ++n)
#pragma unroll
        for (int r = 0; r < 4; ++r) {
          const int row = brow + wr * 64 + m * 16 + lg * 4 + r;
          const int col = bcol + wc * 64 + n * 16 + lr;
          const float vl = (acc[m][n][r] + bias[col]) * sc;
          const int bb = row >> 11, s = row & 2047, hh = col >> 6, hd = col & 63;
          dst[(((size_t)bb * NH + hh) * SEQ + s) * HDIM + hd] = f2bf(vl);
        }
  }
}

__global__ __launch_bounds__(256) void out_gemm(
    const u16* __restrict__ ctxb, const u16* __restrict__ Wob,
    const float* __restrict__ bo, float* __restrict__ outF) {
  __shared__ __align__(16) u32 smem_u32[8192];
  u16* As = (u16*)smem_u32;
  u16* Bs = As + 128 * 64;
  const int brow = blockIdx.y * 128;
  const int bcol = blockIdx.x * 128;
  const int tid = threadIdx.x;
  f32x4 acc[4][4] = {};
  gemm_tile(ctxb, Wob, brow, bcol, tid, As, Bs, acc);
  const int l = tid & 63, wv = tid >> 6;
  const int lr = l & 15, lg = l >> 4;
  const int wr = wv >> 1, wc = wv & 1;
#pragma unroll
  for (int m = 0; m < 4; ++m)
#pragma unroll
    for (int n = 0; n < 4; ++n)
#pragma unroll
      for (int r = 0; r < 4; ++r) {
        const int row = brow + wr * 64 + m * 16 + lg * 4 + r;
        const int col = bcol + wc * 64 + n * 16 + lr;
        outF[(size_t)row * EMB + col] = acc[m][n][r] + bo[col];
      }
}

// ---------------- fused attention: 64 q-rows/wave, two-pass, barrier-free ----------------
// 512 blocks x 4 waves = 2048 waves; wave = 64 q-rows of one (b,h), full K=2048.
// bh = bid&63 -> XCD = bh%8 (8 blocks per bh land on one XCD's L2).
// Logical K/V reads: R10's 3.1 GB -> 1.57 GB (the only lever that has moved attn;
// effective per-CU read rate measured constant ~35 GB/s/CU => time ~ volume).
// TLP drops 4->2 waves/SIMD; compensated by REGISTER-DOUBLE-BUFFERED K prefetch
// (load kt+1 K-frags while computing kt; manual 2x unroll -> static reg indexing).
// Pass 1: QK MFMA -> exp2 -> rowsums (registers only).
// Pass 2 per tile: [K prefetch kt+1] -> V loads -> scores -> pn -> pbuf bf16
//   (swizzled, wave-private) -> PV MFMA -> 16x f32x4 nt stores. NO __syncthreads.
__global__ __launch_bounds__(256) void attn_kernel(
    const u16* __restrict__ qp, const u16* __restrict__ kp, const u16* __restrict__ vpT,
    const u32* __restrict__ bits, const unsigned char* __restrict__ tok,
    float* __restrict__ attn, u16* __restrict__ ctxb) {
  __shared__ __align__(16) u16 pbuf[4][64][64];        // wave-private [wid], 32 KB
  const int tid = threadIdx.x;
  const int l = tid & 63, wid = tid >> 6;
  const int lr = l & 15, lg = l >> 4;
  const int bid = blockIdx.x;                          // 0..511
  const int bh_i = bid & 63;                           // XCD = bh%8
  const int qt = (bid >> 6) * 4 + wid;                 // 0..31
  const int q0 = qt * 64;
  const int h = bh_i & 15, b = bh_i >> 4;
  const size_t bh = (size_t)b * NH + h;
  const u16* qpb = qp + bh * (SEQ * HDIM);
  const u16* kpb = kp + bh * (SEQ * HDIM);
  const u16* vpb = vpT + bh * (HDIM * SEQ);
  float* attb = attn + bh * ((size_t)SEQ * SEQ);
  const unsigned char* tokb = tok + ((size_t)b * 32 + (q0 >> 6)) * 32;
  const u32* bitsb = bits + (size_t)b * SEQ * 64;

  // Q fragments: rows q0 + g*16 + lr, k-dim d*32 + lg*8
  bf16x8 aq[4][2];
#pragma unroll
  for (int g = 0; g < 4; ++g)
#pragma unroll
    for (int d = 0; d < 2; ++d)
      aq[g][d] = ldg8(qpb + (size_t)(q0 + g * 16 + lr) * HDIM + d * 32 + lg * 8);

  auto load_ktile = [&](int kc, bf16x8 (&kf)[4][2]) {
#pragma unroll
    for (int st = 0; st < 4; ++st)
#pragma unroll
      for (int d = 0; d < 2; ++d)
        kf[st][d] = ldg8(kpb + (size_t)(kc + st * 16 + lr) * HDIM + d * 32 + lg * 8);
  };

  // ---- pass 1: rowsums (K prefetched one tile ahead) ----
  float sums[4][4] = {};
  {
    bf16x8 kfA[4][2], kfB[4][2];
    load_ktile(0, kfA);
    auto p1_body = [&](int kt, const bf16x8 (&kf)[4][2]) {
      const int kc = kt * 64;
      const bool okt = tokb[kt] != 0;
#pragma unroll
      for (int g = 0; g < 4; ++g)
#pragma unroll
        for (int st = 0; st < 4; ++st) {
          f32x4 s = {0.f, 0.f, 0.f, 0.f};
          s = mfma16(aq[g][0], kf[st][0], s);
          s = mfma16(aq[g][1], kf[st][1], s);
#pragma unroll
          for (int r = 0; r < 4; ++r) {
            float sc = s[r];
            if (!okt) {
              const int qrow = q0 + g * 16 + lg * 4 + r;
              const int kpos = kc + st * 16 + lr;
              const u32 wb = bitsb[(size_t)qrow * 64 + (kpos >> 5)];
              if (!((wb >> (kpos & 31)) & 1u)) sc = -1e30f;
            }
            sums[g][r] += __builtin_amdgcn_exp2f(sc);
          }
        }
    };
    for (int kt2 = 0; kt2 < 32; kt2 += 2) {
      load_ktile((kt2 + 1) * 64, kfB);
      p1_body(kt2, kfA);
      if (kt2 + 2 < 32) load_ktile((kt2 + 2) * 64, kfA);
      p1_body(kt2 + 1, kfB);
    }
  }
  float rinv[4][4];
#pragma unroll
  for (int g = 0; g < 4; ++g)
#pragma unroll
    for (int r = 0; r < 4; ++r) {
      float vsum = sums[g][r];
      vsum += __shfl_xor(vsum, 1);
      vsum += __shfl_xor(vsum, 2);
      vsum += __shfl_xor(vsum, 4);
      vsum += __shfl_xor(vsum, 8);
      rinv[g][r] = 1.0f / vsum;
    }

  // ---- pass 2: K prefetch + V loads + scores -> pbuf -> PV -> nt stores ----
  f32x4 cacc[4][4] = {};
  {
    bf16x8 kfA[4][2], kfB[4][2];
    load_ktile(0, kfA);
    auto p2_body = [&](int kt, const bf16x8 (&kf)[4][2]) {
      const int kc = kt * 64;
      const bool okt = tokb[kt] != 0;
      // V loads for this tile (consumed after scores -> latency hidden)
      bf16x8 vf[4][2];
#pragma unroll
      for (int ds = 0; ds < 4; ++ds)
#pragma unroll
        for (int x = 0; x < 2; ++x)
          vf[ds][x] = ldg8(vpb + (size_t)(ds * 16 + lr) * SEQ + kc + x * 32 + lg * 8);
#pragma unroll
      for (int g = 0; g < 4; ++g)
#pragma unroll
        for (int st = 0; st < 4; ++st) {
          f32x4 s = {0.f, 0.f, 0.f, 0.f};
          s = mfma16(aq[g][0], kf[st][0], s);
          s = mfma16(aq[g][1], kf[st][1], s);
#pragma unroll
          for (int r = 0; r < 4; ++r) {
            float sc = s[r];
            if (!okt) {
              const int qrow = q0 + g * 16 + lg * 4 + r;
              const int kpos = kc + st * 16 + lr;
              const u32 wb = bitsb[(size_t)qrow * 64 + (kpos >> 5)];
              if (!((wb >> (kpos & 31)) & 1u)) sc = -1e30f;
            }
            const float pn = __builtin_amdgcn_exp2f(sc) * rinv[g][r];
            const int row = g * 16 + lg * 4 + r;
            const int col = st * 16 + lr;
            pbuf[wid][row][col ^ ((row & 7) << 3)] = f2bf(pn);
          }
        }
      // PV: wave-local pbuf readback as A-fragments (normalized bf16)
#pragma unroll
      for (int g = 0; g < 4; ++g)
#pragma unroll
        for (int ks = 0; ks < 2; ++ks) {
          const int prow = g * 16 + lr;
          const int cb = ks * 32 + lg * 8;
          const bf16x8 pa = *reinterpret_cast<const bf16x8*>(
              &pbuf[wid][prow][cb ^ ((prow & 7) << 3)]);
#pragma unroll
          for (int ds = 0; ds < 4; ++ds)
            cacc[g][ds] = mfma16(pa, vf[ds][ks], cacc[g][ds]);
        }
      // vectorized nt attn stores: 16 instrs x 1KB; rows i*4+lg, cols (l&15)*4
#pragma unroll
      for (int i = 0; i < 16; ++i) {
        const int row = i * 4 + lg;
        const int c4 = (l & 15) * 4;
        const u16x4 raw = *reinterpret_cast<const u16x4*>(
            &pbuf[wid][row][c4 ^ ((row & 7) << 3)]);
        f32x4 o;
        o[0] = bf2f(raw[0]); o[1] = bf2f(raw[1]);
        o[2] = bf2f(raw[2]); o[3] = bf2f(raw[3]);
        __builtin_nontemporal_store(
            o, reinterpret_cast<f32x4*>(attb + (size_t)(q0 + row) * SEQ + kc + c4));
      }
    };
    for (int kt2 = 0; kt2 < 32; kt2 += 2) {
      load_ktile((kt2 + 1) * 64, kfB);
      p2_body(kt2, kfA);
      if (kt2 + 2 < 32) load_ktile((kt2 + 2) * 64, kfA);
      p2_body(kt2 + 1, kfB);
    }
  }

  // ctx write: rows q0 + g*16 + lg*4 + r, d-col ds*16+lr (wave-private)
#pragma unroll
  for (int g = 0; g < 4; ++g)
#pragma unroll
    for (int ds = 0; ds < 4; ++ds)
#pragma unroll
      for (int r = 0; r < 4; ++r)
        ctxb[((size_t)b * SEQ + q0 + g * 16 + lg * 4 + r) * EMB + h * HDIM + ds * 16 + lr] =
            f2bf(cacc[g][ds][r]);
}

// ---------------- host launch ----------------
extern "C" void kernel_launch(void* const* d_in, const int* in_sizes, int n_in,
                              void* d_out, int out_size, void* d_ws, size_t ws_size,
                              hipStream_t stream) {
  const float* q   = (const float*)d_in[0];
  const float* k   = (const float*)d_in[1];
  const float* v   = (const float*)d_in[2];
  const int* mask  = (const int*)d_in[3];
  const float* Wk  = (const float*)d_in[4];
  const float* bk  = (const float*)d_in[5];
  const float* Wv  = (const float*)d_in[6];
  const float* bv  = (const float*)d_in[7];
  const float* Wo  = (const float*)d_in[8];
  const float* bo  = (const float*)d_in[9];

  float* outF = (float*)d_out;
  float* attnF = outF + (size_t)NB * SEQ * EMB;

  const size_t MiB = 1024 * 1024;
  char* ws = (char*)d_ws;
  u16* qb   = (u16*)(ws + 0 * MiB);
  u16* kb   = (u16*)(ws + 16 * MiB);
  u16* vb   = (u16*)(ws + 32 * MiB);
  u16* Wvb  = (u16*)(ws + 48 * MiB);
  u16* Wkb  = (u16*)(ws + 50 * MiB);
  u16* Wob  = (u16*)(ws + 52 * MiB);
  u16* qpB  = (u16*)(ws + 54 * MiB);
  u16* kpB  = (u16*)(ws + 70 * MiB);
  u16* vpT  = (u16*)(ws + 86 * MiB);
  u16* ctxb = (u16*)(ws + 102 * MiB);
  u32* bits = (u32*)(ws + 118 * MiB);
  unsigned char* tok = (unsigned char*)(ws + 120 * MiB);

  prep_kernel<<<dim3(NB * SEQ * EMB / 8 / 256, 7), 256, 0, stream>>>(
      q, k, v, Wk, Wv, Wo, mask, qb, kb, vb, Wkb, Wvb, Wob, bits);

  tileok_kernel<<<NB * 32 * 32 / 256, 256, 0, stream>>>(bits, tok);

  proj_gemm<<<dim3(EMB / 128, NB * SEQ / 128, 3), 256, 0, stream>>>(
      qb, kb, vb, Wvb, Wkb, bv, bk, qpB, kpB, vpT);

  attn_kernel<<<512, 256, 0, stream>>>(
      qpB, kpB, vpT, bits, tok, attnF, ctxb);

  out_gemm<<<dim3(EMB / 128, NB * SEQ / 128), 256, 0, stream>>>(ctxb, Wob, bo, outF);
}

// Round 15
// 479.488 us; speedup vs baseline: 1.3110x; 1.2341x over previous
//
#include <hip/hip_runtime.h>
#include <stdint.h>

typedef unsigned short u16;
typedef unsigned int u32;
typedef float f32x4 __attribute__((ext_vector_type(4)));
typedef __bf16 bf16x8 __attribute__((ext_vector_type(8)));
typedef u16 u16x8 __attribute__((ext_vector_type(8)));
typedef u16 u16x4 __attribute__((ext_vector_type(4)));

// Problem geometry (fixed)
#define NB   4
#define SEQ  2048
#define EMB  1024
#define NH   16
#define HDIM 64

#define QSCALE 0.18033688011112042f   // log2(e)/8, folded into qp at projection

__device__ __forceinline__ f32x4 mfma16(bf16x8 a, bf16x8 b, f32x4 c) {
  return __builtin_amdgcn_mfma_f32_16x16x32_bf16(a, b, c, 0, 0, 0);
}
__device__ __forceinline__ u16 f2bf(float f) {
  u32 u = __builtin_bit_cast(u32, f);
  u += 0x7FFFu + ((u >> 16) & 1u);      // round-to-nearest-even
  return (u16)(u >> 16);
}
__device__ __forceinline__ u32 pk2bf(float lo, float hi) {
  return (u32)f2bf(lo) | ((u32)f2bf(hi) << 16);
}
__device__ __forceinline__ float bf2f(u16 h) {
  return __builtin_bit_cast(float, (u32)h << 16);
}
__device__ __forceinline__ bf16x8 ldg8(const u16* p) {
  return *reinterpret_cast<const bf16x8*>(p);
}

// ---------------- prep: fp32->bf16 cvt (y=0..5) + mask bitpack (y=6) ----------------
__global__ __launch_bounds__(256) void prep_kernel(
    const float* __restrict__ q, const float* __restrict__ k, const float* __restrict__ v,
    const float* __restrict__ Wk, const float* __restrict__ Wv, const float* __restrict__ Wo,
    const int* __restrict__ mask,
    u16* __restrict__ qb, u16* __restrict__ kb, u16* __restrict__ vb,
    u16* __restrict__ Wkb, u16* __restrict__ Wvb, u16* __restrict__ Wob,
    u32* __restrict__ bits) {
  const int y = blockIdx.y;
  if (y == 6) {
    const int idx = blockIdx.x * 256 + threadIdx.x;
    if (idx >= NB * SEQ * 64) return;
    const int w = idx & 63;
    const size_t rowbase = (size_t)(idx >> 6) * SEQ;
    const int4* p = reinterpret_cast<const int4*>(mask + rowbase + w * 32);
    u32 m = 0;
#pragma unroll
    for (int j = 0; j < 8; ++j) {
      int4 v4 = p[j];
      m |= (v4.x != 0 ? 1u : 0u) << (j * 4 + 0);
      m |= (v4.y != 0 ? 1u : 0u) << (j * 4 + 1);
      m |= (v4.z != 0 ? 1u : 0u) << (j * 4 + 2);
      m |= (v4.w != 0 ? 1u : 0u) << (j * 4 + 3);
    }
    bits[idx] = m;
    return;
  }
  const float* src; u16* dst; int n8;
  switch (y) {
    case 0: src = q;  dst = qb;  n8 = NB * SEQ * EMB / 8; break;
    case 1: src = k;  dst = kb;  n8 = NB * SEQ * EMB / 8; break;
    case 2: src = v;  dst = vb;  n8 = NB * SEQ * EMB / 8; break;
    case 3: src = Wk; dst = Wkb; n8 = EMB * EMB / 8; break;
    case 4: src = Wv; dst = Wvb; n8 = EMB * EMB / 8; break;
    default: src = Wo; dst = Wob; n8 = EMB * EMB / 8; break;
  }
  int i = blockIdx.x * 256 + threadIdx.x;
  if (i >= n8) return;
  const float4* s = reinterpret_cast<const float4*>(src) + (size_t)i * 2;
  float4 a = s[0], b = s[1];
  u16x8 o;
  o[0] = f2bf(a.x); o[1] = f2bf(a.y); o[2] = f2bf(a.z); o[3] = f2bf(a.w);
  o[4] = f2bf(b.x); o[5] = f2bf(b.y); o[6] = f2bf(b.z); o[7] = f2bf(b.w);
  reinterpret_cast<u16x8*>(dst)[i] = o;
}

// per (b, 64-row qtile, 64-col ktile): 1 if fully unmasked
__global__ __launch_bounds__(256) void tileok_kernel(const u32* __restrict__ bits,
                                                     unsigned char* __restrict__ tok) {
  const int idx = blockIdx.x * 256 + threadIdx.x;      // < 4*32*32
  const int b = idx >> 10, qt = (idx >> 5) & 31, kt = idx & 31;
  const u32* bb = bits + (size_t)b * SEQ * 64;
  u32 acc = 0xFFFFFFFFu;
  for (int rr = 0; rr < 64; ++rr) {
    const u32* pr = bb + (size_t)(qt * 64 + rr) * 64 + kt * 2;
    acc &= pr[0] & pr[1];
  }
  tok[idx] = (acc == 0xFFFFFFFFu) ? 1 : 0;
}

// ---------------- 128x128x(K=1024) bf16 GEMM mainloop (m97 structure) ----------------
__device__ __forceinline__ void gemm_tile(const u16* __restrict__ A,
                                          const u16* __restrict__ W,
                                          int brow, int bcol, int tid,
                                          u16* As, u16* Bs, f32x4 acc[4][4]) {
  const int K = 1024;
  const int l = tid & 63, wv = tid >> 6;
  const int lr = l & 15, lg = l >> 4;
  const int wr = wv >> 1, wc = wv & 1;
  const int srow = l >> 3;
  const int skb = (l & 7) * 16;

  for (int k0 = 0; k0 < K; k0 += 64) {
#pragma unroll
    for (int r = 0; r < 4; ++r) {
      const int chunk = r * 4 + wv;
      const int row = chunk * 8 + srow;
      const char* ga = (const char*)A + ((size_t)(brow + row) * K + k0) * 2 + skb;
      const char* gb = (const char*)W + ((size_t)(bcol + row) * K + k0) * 2 + skb;
      __builtin_amdgcn_global_load_lds(
          (const __attribute__((address_space(1))) u32*)ga,
          (__attribute__((address_space(3))) u32*)((char*)As + chunk * 1024), 16, 0, 0);
      __builtin_amdgcn_global_load_lds(
          (const __attribute__((address_space(1))) u32*)gb,
          (__attribute__((address_space(3))) u32*)((char*)Bs + chunk * 1024), 16, 0, 0);
    }
    __syncthreads();
#pragma unroll
    for (int ks = 0; ks < 2; ++ks) {
      bf16x8 af[4], bfr[4];
#pragma unroll
      for (int m = 0; m < 4; ++m)
        af[m] = *reinterpret_cast<const bf16x8*>(
            (const char*)As + (wr * 64 + m * 16 + lr) * 128 + ks * 64 + lg * 16);
#pragma unroll
      for (int n = 0; n < 4; ++n)
        bfr[n] = *reinterpret_cast<const bf16x8*>(
            (const char*)Bs + (wc * 64 + n * 16 + lr) * 128 + ks * 64 + lg * 16);
#pragma unroll
      for (int m = 0; m < 4; ++m)
#pragma unroll
        for (int n = 0; n < 4; ++n)
          acc[m][n] = mfma16(af[m], bfr[n], acc[m][n]);
    }
    __syncthreads();
  }
}

// z=0: qp = (q@Wv^T+bv)*QSCALE  [B][H][S][HD]
// z=1: kp = k@Wk^T+bk           [B][H][S][HD]
// z=2: vpT = v@Wv^T+bv          [B][H][HD][S] (transposed via LDS)
__global__ __launch_bounds__(256) void proj_gemm(
    const u16* __restrict__ qb, const u16* __restrict__ kb, const u16* __restrict__ vb,
    const u16* __restrict__ Wvb, const u16* __restrict__ Wkb,
    const float* __restrict__ bv, const float* __restrict__ bkp,
    u16* __restrict__ qp, u16* __restrict__ kp, u16* __restrict__ vpT) {
  __shared__ __align__(16) u32 smem_u32[8192];
  u16* As = (u16*)smem_u32;
  u16* Bs = As + 128 * 64;
  const int z = blockIdx.z;
  const u16* A = (z == 0) ? qb : (z == 1) ? kb : vb;
  const u16* W = (z == 1) ? Wkb : Wvb;
  const float* bias = (z == 1) ? bkp : bv;
  const int brow = blockIdx.y * 128;
  const int bcol = blockIdx.x * 128;
  const int tid = threadIdx.x;
  f32x4 acc[4][4] = {};
  gemm_tile(A, W, brow, bcol, tid, As, Bs, acc);
  const int l = tid & 63, wv = tid >> 6;
  const int lr = l & 15, lg = l >> 4;
  const int wr = wv >> 1, wc = wv & 1;

  if (z == 2) {
#pragma unroll
    for (int m = 0; m < 4; ++m)
#pragma unroll
      for (int n = 0; n < 4; ++n) {
        const int cl = wc * 64 + n * 16 + lr;
        const float b0 = bias[bcol + cl];
        const u32 w0 = pk2bf(acc[m][n][0] + b0, acc[m][n][1] + b0);
        const u32 w1 = pk2bf(acc[m][n][2] + b0, acc[m][n][3] + b0);
        const int rp0 = wr * 32 + m * 8 + lg * 2;
        const int a32 = cl * 64 + (rp0 ^ ((lr & 7) << 2));
        uint2 wv2; wv2.x = w0; wv2.y = w1;
        *reinterpret_cast<uint2*>(&smem_u32[a32]) = wv2;
      }
    __syncthreads();
#pragma unroll
    for (int i = 0; i < 8; ++i) {
      const int idx = i * 256 + tid;
      const int cl = idx >> 4;
      const int rp0 = (idx & 15) * 4;
      const int a32 = cl * 64 + (rp0 ^ ((cl & 7) << 2));
      const uint4 d = *reinterpret_cast<const uint4*>(&smem_u32[a32]);
      const int col = bcol + cl, hh = col >> 6, hd = col & 63;
      const int row = brow + rp0 * 2, bb = row >> 11, s = row & 2047;
      *reinterpret_cast<uint4*>(
          vpT + ((((size_t)bb * NH + hh) * HDIM + hd) * SEQ + s)) = d;
    }
  } else {
    u16* dst = (z == 0) ? qp : kp;
    const float sc = (z == 0) ? QSCALE : 1.0f;
#pragma unroll
    for (int m = 0; m < 4; ++m)
#pragma unroll
      for (int n = 0; n < 4; ++n)
#pragma unroll
        for (int r = 0; r < 4; ++r) {
          const int row = brow + wr * 64 + m * 16 + lg * 4 + r;
          const int col = bcol + wc * 64 + n * 16 + lr;
          const float vl = (acc[m][n][r] + bias[col]) * sc;
          const int bb = row >> 11, s = row & 2047, hh = col >> 6, hd = col & 63;
          dst[(((size_t)bb * NH + hh) * SEQ + s) * HDIM + hd] = f2bf(vl);
        }
  }
}

__global__ __launch_bounds__(256) void out_gemm(
    const u16* __restrict__ ctxb, const u16* __restrict__ Wob,
    const float* __restrict__ bo, float* __restrict__ outF) {
  __shared__ __align__(16) u32 smem_u32[8192];
  u16* As = (u16*)smem_u32;
  u16* Bs = As + 128 * 64;
  const int brow = blockIdx.y * 128;
  const int bcol = blockIdx.x * 128;
  const int tid = threadIdx.x;
  f32x4 acc[4][4] = {};
  gemm_tile(ctxb, Wob, brow, bcol, tid, As, Bs, acc);
  const int l = tid & 63, wv = tid >> 6;
  const int lr = l & 15, lg = l >> 4;
  const int wr = wv >> 1, wc = wv & 1;
#pragma unroll
  for (int m = 0; m < 4; ++m)
#pragma unroll
    for (int n = 0; n < 4; ++n)
#pragma unroll
      for (int r = 0; r < 4; ++r) {
        const int row = brow + wr * 64 + m * 16 + lg * 4 + r;
        const int col = bcol + wc * 64 + n * 16 + lr;
        outF[(size_t)row * EMB + col] = acc[m][n][r] + bo[col];
      }
}

// ---------------- fused attention: R10 structure + staged pass 1 ----------------
// 1024 blocks x 4 waves; wave = 32 q-rows of one (b,h), full K=2048.
// XCD swizzle (R2): swz=(bid&7)*128+(bid>>3); Wn=swz*4+wid; qt=Wn&63; the 4 waves
// of a block share one (b,h) -> block-cooperative K staging is free reuse.
// Pass 1 (no stores in flight): double-buffered block staging of the K tile via
//   global_load_lds w/ pre-swizzled dense source (8 full lines/instr; R13-verified
//   layout). Pipeline per tile: s_waitcnt vmcnt(0) -> s_barrier -> ds_read frags
//   -> issue stage(kt+1) -> compute. Stage of kt+1 flies under compute of kt;
//   vmcnt(0) is exact because pass 1 has NO stores outstanding.
// Pass 2: R10 verbatim (direct K/V loads, pbuf, PV, 8x f32x4 nt stores, no sync).
__global__ __launch_bounds__(256) void attn_kernel(
    const u16* __restrict__ qp, const u16* __restrict__ kp, const u16* __restrict__ vpT,
    const u32* __restrict__ bits, const unsigned char* __restrict__ tok,
    float* __restrict__ attn, u16* __restrict__ ctxb) {
  __shared__ __align__(16) u16 pbuf[4][32][64];        // wave-private [wid], 16 KB
  __shared__ __align__(16) u16 Ks[2][4096];            // 16 KB, block-shared K tile
  const int tid = threadIdx.x;
  const int l = tid & 63, wid = tid >> 6;
  const int lr = l & 15, lg = l >> 4;
  const int bid = blockIdx.x;
  const int swz = (bid & 7) * 128 + (bid >> 3);
  const int Wn = swz * 4 + wid;                        // 0..4095
  const int qt = Wn & 63, h = (Wn >> 6) & 15, b = Wn >> 10;
  const int q0 = qt * 32;
  const size_t bh = (size_t)b * NH + h;
  const u16* qpb = qp + bh * (SEQ * HDIM);
  const u16* kpb = kp + bh * (SEQ * HDIM);
  const u16* vpb = vpT + bh * (HDIM * SEQ);
  float* attb = attn + bh * ((size_t)SEQ * SEQ);
  const unsigned char* tokb = tok + ((size_t)b * 32 + (qt >> 1)) * 32;
  const u32* bitsb = bits + (size_t)b * SEQ * 64;

  // Q fragments: rows q0 + g*16 + lr, k-dim d*32 + lg*8
  bf16x8 aq[2][2];
#pragma unroll
  for (int g = 0; g < 2; ++g)
#pragma unroll
    for (int d = 0; d < 2; ++d)
      aq[g][d] = ldg8(qpb + (size_t)(q0 + g * 16 + lr) * HDIM + d * 32 + lg * 8);

  // block-cooperative K tile stage (dense 16B granules, source pre-swizzled)
  auto stage_k = [&](int kt, int bufi) {
#pragma unroll
    for (int c = 0; c < 2; ++c) {
      const int gi = c * 256 + tid;                    // 0..511 = row*8 + cs
      const int row = gi >> 3, cs = gi & 7;
      const int csx = cs ^ (row & 7);
      __builtin_amdgcn_global_load_lds(
          (const __attribute__((address_space(1))) u32*)
              ((const char*)(kpb + (size_t)(kt * 64 + row) * HDIM) + csx * 16),
          (__attribute__((address_space(3))) u32*)
              ((char*)&Ks[bufi][0] + c * 4096 + wid * 1024),
          16, 0, 0);
    }
  };

  // ---- pass 1: rowsums from staged K ----
  float sums[2][4] = {{0.f, 0.f, 0.f, 0.f}, {0.f, 0.f, 0.f, 0.f}};
  stage_k(0, 0);
  for (int kt = 0; kt < 32; ++kt) {
    const int cur = kt & 1;
    asm volatile("s_waitcnt vmcnt(0)" ::: "memory");   // own stage(kt) landed
    __builtin_amdgcn_sched_barrier(0);
    __builtin_amdgcn_s_barrier();                      // all waves' stage landed
    // fragments from Ks[cur] (read granule g at physical g^(row&7): 8 banks/8 rows)
    bf16x8 bk8[4][2];
#pragma unroll
    for (int st = 0; st < 4; ++st)
#pragma unroll
      for (int d = 0; d < 2; ++d) {
        const int row = st * 16 + lr;
        bk8[st][d] = *reinterpret_cast<const bf16x8*>(
            &Ks[cur][(((row << 3) | ((d * 4 + lg) ^ (row & 7)))) << 3]);
      }
    if (kt + 1 < 32) stage_k(kt + 1, cur ^ 1);         // flies under compute
    const int kc = kt * 64;
    const bool okt = tokb[kt] != 0;
#pragma unroll
    for (int g = 0; g < 2; ++g)
#pragma unroll
      for (int st = 0; st < 4; ++st) {
        f32x4 s = {0.f, 0.f, 0.f, 0.f};
        s = mfma16(aq[g][0], bk8[st][0], s);
        s = mfma16(aq[g][1], bk8[st][1], s);
#pragma unroll
        for (int r = 0; r < 4; ++r) {
          float sc = s[r];
          if (!okt) {
            const int qrow = q0 + g * 16 + lg * 4 + r;
            const int kpos = kc + st * 16 + lr;
            const u32 wb = bitsb[(size_t)qrow * 64 + (kpos >> 5)];
            if (!((wb >> (kpos & 31)) & 1u)) sc = -1e30f;
          }
          sums[g][r] += __builtin_amdgcn_exp2f(sc);
        }
      }
  }
  float rinv[2][4];
#pragma unroll
  for (int g = 0; g < 2; ++g)
#pragma unroll
    for (int r = 0; r < 4; ++r) {
      float vsum = sums[g][r];
      vsum += __shfl_xor(vsum, 1);
      vsum += __shfl_xor(vsum, 2);
      vsum += __shfl_xor(vsum, 4);
      vsum += __shfl_xor(vsum, 8);
      rinv[g][r] = 1.0f / vsum;
    }
  __syncthreads();                                     // pass1/pass2 phase split

  // ---- pass 2 (R10 verbatim: direct loads, barrier-free) ----
  f32x4 cacc[2][4] = {};
  for (int kt = 0; kt < 32; ++kt) {
    const int kc = kt * 64;
    const bool okt = tokb[kt] != 0;
    bf16x8 bk8[4][2];
#pragma unroll
    for (int st = 0; st < 4; ++st)
#pragma unroll
      for (int d = 0; d < 2; ++d)
        bk8[st][d] = ldg8(kpb + (size_t)(kc + st * 16 + lr) * HDIM + d * 32 + lg * 8);
#pragma unroll
    for (int g = 0; g < 2; ++g)
#pragma unroll
      for (int st = 0; st < 4; ++st) {
        f32x4 s = {0.f, 0.f, 0.f, 0.f};
        s = mfma16(aq[g][0], bk8[st][0], s);
        s = mfma16(aq[g][1], bk8[st][1], s);
#pragma unroll
        for (int r = 0; r < 4; ++r) {
          float sc = s[r];
          if (!okt) {
            const int qrow = q0 + g * 16 + lg * 4 + r;
            const int kpos = kc + st * 16 + lr;
            const u32 wb = bitsb[(size_t)qrow * 64 + (kpos >> 5)];
            if (!((wb >> (kpos & 31)) & 1u)) sc = -1e30f;
          }
          const float pn = __builtin_amdgcn_exp2f(sc) * rinv[g][r];
          const int row = g * 16 + lg * 4 + r;
          const int col = st * 16 + lr;
          pbuf[wid][row][col ^ ((row & 7) << 3)] = f2bf(pn);
        }
      }
    // V loads after scores: bk8 dead -> vf reuses registers (lower peak VGPR)
    bf16x8 vf[4][2];
#pragma unroll
    for (int ds = 0; ds < 4; ++ds)
#pragma unroll
      for (int x = 0; x < 2; ++x)
        vf[ds][x] = ldg8(vpb + (size_t)(ds * 16 + lr) * SEQ + kc + x * 32 + lg * 8);
    // PV: wave-local pbuf readback as A-fragments (normalized bf16)
#pragma unroll
    for (int g = 0; g < 2; ++g)
#pragma unroll
      for (int ks = 0; ks < 2; ++ks) {
        const int prow = g * 16 + lr;
        const int cb = ks * 32 + lg * 8;
        const bf16x8 pa = *reinterpret_cast<const bf16x8*>(
            &pbuf[wid][prow][cb ^ ((prow & 7) << 3)]);
#pragma unroll
        for (int ds = 0; ds < 4; ++ds)
          cacc[g][ds] = mfma16(pa, vf[ds][ks], cacc[g][ds]);
      }
    // vectorized nt attn stores: 8 instrs x 1KB; rows i*4+lg, cols (l&15)*4
#pragma unroll
    for (int i = 0; i < 8; ++i) {
      const int row = i * 4 + lg;
      const int c4 = (l & 15) * 4;
      const u16x4 raw = *reinterpret_cast<const u16x4*>(
          &pbuf[wid][row][c4 ^ ((row & 7) << 3)]);
      f32x4 o;
      o[0] = bf2f(raw[0]); o[1] = bf2f(raw[1]);
      o[2] = bf2f(raw[2]); o[3] = bf2f(raw[3]);
      __builtin_nontemporal_store(
          o, reinterpret_cast<f32x4*>(attb + (size_t)(q0 + row) * SEQ + kc + c4));
    }
  }

  // ctx write: rows q0 + g*16 + lg*4 + r, d-col ds*16+lr
#pragma unroll
  for (int g = 0; g < 2; ++g)
#pragma unroll
    for (int ds = 0; ds < 4; ++ds)
#pragma unroll
      for (int r = 0; r < 4; ++r)
        ctxb[((size_t)b * SEQ + q0 + g * 16 + lg * 4 + r) * EMB + h * HDIM + ds * 16 + lr] =
            f2bf(cacc[g][ds][r]);
}

// ---------------- host launch ----------------
extern "C" void kernel_launch(void* const* d_in, const int* in_sizes, int n_in,
                              void* d_out, int out_size, void* d_ws, size_t ws_size,
                              hipStream_t stream) {
  const float* q   = (const float*)d_in[0];
  const float* k   = (const float*)d_in[1];
  const float* v   = (const float*)d_in[2];
  const int* mask  = (const int*)d_in[3];
  const float* Wk  = (const float*)d_in[4];
  const float* bk  = (const float*)d_in[5];
  const float* Wv  = (const float*)d_in[6];
  const float* bv  = (const float*)d_in[7];
  const float* Wo  = (const float*)d_in[8];
  const float* bo  = (const float*)d_in[9];

  float* outF = (float*)d_out;
  float* attnF = outF + (size_t)NB * SEQ * EMB;

  const size_t MiB = 1024 * 1024;
  char* ws = (char*)d_ws;
  u16* qb   = (u16*)(ws + 0 * MiB);
  u16* kb   = (u16*)(ws + 16 * MiB);
  u16* vb   = (u16*)(ws + 32 * MiB);
  u16* Wvb  = (u16*)(ws + 48 * MiB);
  u16* Wkb  = (u16*)(ws + 50 * MiB);
  u16* Wob  = (u16*)(ws + 52 * MiB);
  u16* qpB  = (u16*)(ws + 54 * MiB);
  u16* kpB  = (u16*)(ws + 70 * MiB);
  u16* vpT  = (u16*)(ws + 86 * MiB);
  u16* ctxb = (u16*)(ws + 102 * MiB);
  u32* bits = (u32*)(ws + 118 * MiB);
  unsigned char* tok = (unsigned char*)(ws + 120 * MiB);

  prep_kernel<<<dim3(NB * SEQ * EMB / 8 / 256, 7), 256, 0, stream>>>(
      q, k, v, Wk, Wv, Wo, mask, qb, kb, vb, Wkb, Wvb, Wob, bits);

  tileok_kernel<<<NB * 32 * 32 / 256, 256, 0, stream>>>(bits, tok);

  proj_gemm<<<dim3(EMB / 128, NB * SEQ / 128, 3), 256, 0, stream>>>(
      qb, kb, vb, Wvb, Wkb, bv, bk, qpB, kpB, vpT);

  attn_kernel<<<1024, 256, 0, stream>>>(
      qpB, kpB, vpT, bits, tok, attnF, ctxb);

  out_gemm<<<dim3(EMB / 128, NB * SEQ / 128), 256, 0, stream>>>(ctxb, Wob, bo, outF);
}

// Round 16
// 427.407 us; speedup vs baseline: 1.4708x; 1.1219x over previous
//
#include <hip/hip_runtime.h>
#include <stdint.h>

typedef unsigned short u16;
typedef unsigned int u32;
typedef float f32x4 __attribute__((ext_vector_type(4)));
typedef __bf16 bf16x8 __attribute__((ext_vector_type(8)));
typedef u16 u16x8 __attribute__((ext_vector_type(8)));
typedef u16 u16x4 __attribute__((ext_vector_type(4)));

// Problem geometry (fixed)
#define NB   4
#define SEQ  2048
#define EMB  1024
#define NH   16
#define HDIM 64

#define QSCALE 0.18033688011112042f   // log2(e)/8, folded into qp at projection

__device__ __forceinline__ f32x4 mfma16(bf16x8 a, bf16x8 b, f32x4 c) {
  return __builtin_amdgcn_mfma_f32_16x16x32_bf16(a, b, c, 0, 0, 0);
}
__device__ __forceinline__ u16 f2bf(float f) {
  u32 u = __builtin_bit_cast(u32, f);
  u += 0x7FFFu + ((u >> 16) & 1u);      // round-to-nearest-even
  return (u16)(u >> 16);
}
__device__ __forceinline__ u32 pk2bf(float lo, float hi) {
  return (u32)f2bf(lo) | ((u32)f2bf(hi) << 16);
}
__device__ __forceinline__ float bf2f(u16 h) {
  return __builtin_bit_cast(float, (u32)h << 16);
}
__device__ __forceinline__ bf16x8 ldg8(const u16* p) {
  return *reinterpret_cast<const bf16x8*>(p);
}

// ---------------- prep: fp32->bf16 cvt (y=0..5) + mask bitpack (y=6) ----------------
__global__ __launch_bounds__(256) void prep_kernel(
    const float* __restrict__ q, const float* __restrict__ k, const float* __restrict__ v,
    const float* __restrict__ Wk, const float* __restrict__ Wv, const float* __restrict__ Wo,
    const int* __restrict__ mask,
    u16* __restrict__ qb, u16* __restrict__ kb, u16* __restrict__ vb,
    u16* __restrict__ Wkb, u16* __restrict__ Wvb, u16* __restrict__ Wob,
    u32* __restrict__ bits) {
  const int y = blockIdx.y;
  if (y == 6) {
    const int idx = blockIdx.x * 256 + threadIdx.x;
    if (idx >= NB * SEQ * 64) return;
    const int w = idx & 63;
    const size_t rowbase = (size_t)(idx >> 6) * SEQ;
    const int4* p = reinterpret_cast<const int4*>(mask + rowbase + w * 32);
    u32 m = 0;
#pragma unroll
    for (int j = 0; j < 8; ++j) {
      int4 v4 = p[j];
      m |= (v4.x != 0 ? 1u : 0u) << (j * 4 + 0);
      m |= (v4.y != 0 ? 1u : 0u) << (j * 4 + 1);
      m |= (v4.z != 0 ? 1u : 0u) << (j * 4 + 2);
      m |= (v4.w != 0 ? 1u : 0u) << (j * 4 + 3);
    }
    bits[idx] = m;
    return;
  }
  const float* src; u16* dst; int n8;
  switch (y) {
    case 0: src = q;  dst = qb;  n8 = NB * SEQ * EMB / 8; break;
    case 1: src = k;  dst = kb;  n8 = NB * SEQ * EMB / 8; break;
    case 2: src = v;  dst = vb;  n8 = NB * SEQ * EMB / 8; break;
    case 3: src = Wk; dst = Wkb; n8 = EMB * EMB / 8; break;
    case 4: src = Wv; dst = Wvb; n8 = EMB * EMB / 8; break;
    default: src = Wo; dst = Wob; n8 = EMB * EMB / 8; break;
  }
  int i = blockIdx.x * 256 + threadIdx.x;
  if (i >= n8) return;
  const float4* s = reinterpret_cast<const float4*>(src) + (size_t)i * 2;
  float4 a = s[0], b = s[1];
  u16x8 o;
  o[0] = f2bf(a.x); o[1] = f2bf(a.y); o[2] = f2bf(a.z); o[3] = f2bf(a.w);
  o[4] = f2bf(b.x); o[5] = f2bf(b.y); o[6] = f2bf(b.z); o[7] = f2bf(b.w);
  reinterpret_cast<u16x8*>(dst)[i] = o;
}

// per (b, 64-row qtile, 64-col ktile): 1 if fully unmasked
__global__ __launch_bounds__(256) void tileok_kernel(const u32* __restrict__ bits,
                                                     unsigned char* __restrict__ tok) {
  const int idx = blockIdx.x * 256 + threadIdx.x;      // < 4*32*32
  const int b = idx >> 10, qt = (idx >> 5) & 31, kt = idx & 31;
  const u32* bb = bits + (size_t)b * SEQ * 64;
  u32 acc = 0xFFFFFFFFu;
  for (int rr = 0; rr < 64; ++rr) {
    const u32* pr = bb + (size_t)(qt * 64 + rr) * 64 + kt * 2;
    acc &= pr[0] & pr[1];
  }
  tok[idx] = (acc == 0xFFFFFFFFu) ? 1 : 0;
}

// ---------------- 128x128x(K=1024) bf16 GEMM mainloop (m97 structure) ----------------
__device__ __forceinline__ void gemm_tile(const u16* __restrict__ A,
                                          const u16* __restrict__ W,
                                          int brow, int bcol, int tid,
                                          u16* As, u16* Bs, f32x4 acc[4][4]) {
  const int K = 1024;
  const int l = tid & 63, wv = tid >> 6;
  const int lr = l & 15, lg = l >> 4;
  const int wr = wv >> 1, wc = wv & 1;
  const int srow = l >> 3;
  const int skb = (l & 7) * 16;

  for (int k0 = 0; k0 < K; k0 += 64) {
#pragma unroll
    for (int r = 0; r < 4; ++r) {
      const int chunk = r * 4 + wv;
      const int row = chunk * 8 + srow;
      const char* ga = (const char*)A + ((size_t)(brow + row) * K + k0) * 2 + skb;
      const char* gb = (const char*)W + ((size_t)(bcol + row) * K + k0) * 2 + skb;
      __builtin_amdgcn_global_load_lds(
          (const __attribute__((address_space(1))) u32*)ga,
          (__attribute__((address_space(3))) u32*)((char*)As + chunk * 1024), 16, 0, 0);
      __builtin_amdgcn_global_load_lds(
          (const __attribute__((address_space(1))) u32*)gb,
          (__attribute__((address_space(3))) u32*)((char*)Bs + chunk * 1024), 16, 0, 0);
    }
    __syncthreads();
#pragma unroll
    for (int ks = 0; ks < 2; ++ks) {
      bf16x8 af[4], bfr[4];
#pragma unroll
      for (int m = 0; m < 4; ++m)
        af[m] = *reinterpret_cast<const bf16x8*>(
            (const char*)As + (wr * 64 + m * 16 + lr) * 128 + ks * 64 + lg * 16);
#pragma unroll
      for (int n = 0; n < 4; ++n)
        bfr[n] = *reinterpret_cast<const bf16x8*>(
            (const char*)Bs + (wc * 64 + n * 16 + lr) * 128 + ks * 64 + lg * 16);
#pragma unroll
      for (int m = 0; m < 4; ++m)
#pragma unroll
        for (int n = 0; n < 4; ++n)
          acc[m][n] = mfma16(af[m], bfr[n], acc[m][n]);
    }
    __syncthreads();
  }
}

// z=0: qp = (q@Wv^T+bv)*QSCALE  [B][H][S][HD]
// z=1: kp = k@Wk^T+bk           [B][H][S][HD]
// z=2: vpT = v@Wv^T+bv          [B][H][HD][S] (transposed via LDS)
__global__ __launch_bounds__(256) void proj_gemm(
    const u16* __restrict__ qb, const u16* __restrict__ kb, const u16* __restrict__ vb,
    const u16* __restrict__ Wvb, const u16* __restrict__ Wkb,
    const float* __restrict__ bv, const float* __restrict__ bkp,
    u16* __restrict__ qp, u16* __restrict__ kp, u16* __restrict__ vpT) {
  __shared__ __align__(16) u32 smem_u32[8192];
  u16* As = (u16*)smem_u32;
  u16* Bs = As + 128 * 64;
  const int z = blockIdx.z;
  const u16* A = (z == 0) ? qb : (z == 1) ? kb : vb;
  const u16* W = (z == 1) ? Wkb : Wvb;
  const float* bias = (z == 1) ? bkp : bv;
  const int brow = blockIdx.y * 128;
  const int bcol = blockIdx.x * 128;
  const int tid = threadIdx.x;
  f32x4 acc[4][4] = {};
  gemm_tile(A, W, brow, bcol, tid, As, Bs, acc);
  const int l = tid & 63, wv = tid >> 6;
  const int lr = l & 15, lg = l >> 4;
  const int wr = wv >> 1, wc = wv & 1;

  if (z == 2) {
#pragma unroll
    for (int m = 0; m < 4; ++m)
#pragma unroll
      for (int n = 0; n < 4; ++n) {
        const int cl = wc * 64 + n * 16 + lr;
        const float b0 = bias[bcol + cl];
        const u32 w0 = pk2bf(acc[m][n][0] + b0, acc[m][n][1] + b0);
        const u32 w1 = pk2bf(acc[m][n][2] + b0, acc[m][n][3] + b0);
        const int rp0 = wr * 32 + m * 8 + lg * 2;
        const int a32 = cl * 64 + (rp0 ^ ((lr & 7) << 2));
        uint2 wv2; wv2.x = w0; wv2.y = w1;
        *reinterpret_cast<uint2*>(&smem_u32[a32]) = wv2;
      }
    __syncthreads();
#pragma unroll
    for (int i = 0; i < 8; ++i) {
      const int idx = i * 256 + tid;
      const int cl = idx >> 4;
      const int rp0 = (idx & 15) * 4;
      const int a32 = cl * 64 + (rp0 ^ ((cl & 7) << 2));
      const uint4 d = *reinterpret_cast<const uint4*>(&smem_u32[a32]);
      const int col = bcol + cl, hh = col >> 6, hd = col & 63;
      const int row = brow + rp0 * 2, bb = row >> 11, s = row & 2047;
      *reinterpret_cast<uint4*>(
          vpT + ((((size_t)bb * NH + hh) * HDIM + hd) * SEQ + s)) = d;
    }
  } else {
    u16* dst = (z == 0) ? qp : kp;
    const float sc = (z == 0) ? QSCALE : 1.0f;
#pragma unroll
    for (int m = 0; m < 4; ++m)
#pragma unroll
      for (int n = 0; n < 4; ++n)
#pragma unroll
        for (int r = 0; r < 4; ++r) {
          const int row = brow + wr * 64 + m * 16 + lg * 4 + r;
          const int col = bcol + wc * 64 + n * 16 + lr;
          const float vl = (acc[m][n][r] + bias[col]) * sc;
          const int bb = row >> 11, s = row & 2047, hh = col >> 6, hd = col & 63;
          dst[(((size_t)bb * NH + hh) * SEQ + s) * HDIM + hd] = f2bf(vl);
        }
  }
}

__global__ __launch_bounds__(256) void out_gemm(
    const u16* __restrict__ ctxb, const u16* __restrict__ Wob,
    const float* __restrict__ bo, float* __restrict__ outF) {
  __shared__ __align__(16) u32 smem_u32[8192];
  u16* As = (u16*)smem_u32;
  u16* Bs = As + 128 * 64;
  const int brow = blockIdx.y * 128;
  const int bcol = blockIdx.x * 128;
  const int tid = threadIdx.x;
  f32x4 acc[4][4] = {};
  gemm_tile(ctxb, Wob, brow, bcol, tid, As, Bs, acc);
  const int l = tid & 63, wv = tid >> 6;
  const int lr = l & 15, lg = l >> 4;
  const int wr = wv >> 1, wc = wv & 1;
#pragma unroll
  for (int m = 0; m < 4; ++m)
#pragma unroll
    for (int n = 0; n < 4; ++n)
#pragma unroll
      for (int r = 0; r < 4; ++r) {
        const int row = brow + wr * 64 + m * 16 + lg * 4 + r;
        const int col = bcol + wc * 64 + n * 16 + lr;
        outF[(size_t)row * EMB + col] = acc[m][n][r] + bo[col];
      }
}

// ---------------- fused attention: staged pass 1 (R15) + staged pass 2 (counted vmcnt) ----
// 1024 blocks x 4 waves; wave = 32 q-rows of one (b,h), full K=2048.
// XCD swizzle: swz=(bid&7)*128+(bid>>3); Wn=swz*4+wid; qt=Wn&63; 4 waves share (b,h).
// Pass 1 (R15-verbatim, verified): double-buffered block K staging, vmcnt(0)+barrier.
// Pass 2: K AND V staged the same way, but with COUNTED vmcnt so the nt attn
//   stores are never drained in-loop (R13's failure was __syncthreads -> vmcnt(0)):
//   per tile: s_waitcnt vmcnt(8) [waits exactly for stage(kt); stores(kt-1)=8
//   youngest stay in flight] -> raw s_barrier -> stage(kt+1) into buf^1 [safe:
//   barrier proves all waves finished reading buf^1 at kt-1] -> ds_read frags
//   -> scores -> pbuf -> PV -> 8 nt stores. FIFO/wave at wait: [stage(kt) 4,
//   stores(kt-1) 8] => vmcnt(8) retires stage(kt) only. kt=0 uses vmcnt(0).
// Logical K/V reads: pass2 2.1 GB -> 0.52 GB. LDS 48 KB -> 3 blocks/CU.
__global__ __launch_bounds__(256) void attn_kernel(
    const u16* __restrict__ qp, const u16* __restrict__ kp, const u16* __restrict__ vpT,
    const u32* __restrict__ bits, const unsigned char* __restrict__ tok,
    float* __restrict__ attn, u16* __restrict__ ctxb) {
  __shared__ __align__(16) u16 pbuf[4][32][64];        // wave-private [wid], 16 KB
  __shared__ __align__(16) u16 Ks[2][4096];            // 16 KB, block-shared K tile
  __shared__ __align__(16) u16 Vs[2][4096];            // 16 KB, block-shared V tile
  const int tid = threadIdx.x;
  const int l = tid & 63, wid = tid >> 6;
  const int lr = l & 15, lg = l >> 4;
  const int bid = blockIdx.x;
  const int swz = (bid & 7) * 128 + (bid >> 3);
  const int Wn = swz * 4 + wid;                        // 0..4095
  const int qt = Wn & 63, h = (Wn >> 6) & 15, b = Wn >> 10;
  const int q0 = qt * 32;
  const size_t bh = (size_t)b * NH + h;
  const u16* qpb = qp + bh * (SEQ * HDIM);
  const u16* kpb = kp + bh * (SEQ * HDIM);
  const u16* vpb = vpT + bh * (HDIM * SEQ);
  float* attb = attn + bh * ((size_t)SEQ * SEQ);
  const unsigned char* tokb = tok + ((size_t)b * 32 + (qt >> 1)) * 32;
  const u32* bitsb = bits + (size_t)b * SEQ * 64;

  // Q fragments: rows q0 + g*16 + lr, k-dim d*32 + lg*8
  bf16x8 aq[2][2];
#pragma unroll
  for (int g = 0; g < 2; ++g)
#pragma unroll
    for (int d = 0; d < 2; ++d)
      aq[g][d] = ldg8(qpb + (size_t)(q0 + g * 16 + lr) * HDIM + d * 32 + lg * 8);

  // block-cooperative tile stages (dense 16B granules, source pre-swizzled)
  auto stage_k = [&](int kt, int bufi) {
#pragma unroll
    for (int c = 0; c < 2; ++c) {
      const int gi = c * 256 + tid;                    // 0..511 = row*8 + cs
      const int row = gi >> 3, cs = gi & 7;
      const int csx = cs ^ (row & 7);
      __builtin_amdgcn_global_load_lds(
          (const __attribute__((address_space(1))) u32*)
              ((const char*)(kpb + (size_t)(kt * 64 + row) * HDIM) + csx * 16),
          (__attribute__((address_space(3))) u32*)
              ((char*)&Ks[bufi][0] + c * 4096 + wid * 1024),
          16, 0, 0);
    }
  };
  auto stage_v = [&](int kt, int bufi) {
#pragma unroll
    for (int c = 0; c < 2; ++c) {
      const int gi = c * 256 + tid;                    // row = hd index, cs granule
      const int row = gi >> 3, cs = gi & 7;
      const int csx = cs ^ (row & 7);
      __builtin_amdgcn_global_load_lds(
          (const __attribute__((address_space(1))) u32*)
              ((const char*)(vpb + (size_t)row * SEQ + kt * 64) + csx * 16),
          (__attribute__((address_space(3))) u32*)
              ((char*)&Vs[bufi][0] + c * 4096 + wid * 1024),
          16, 0, 0);
    }
  };

  // ---- pass 1: rowsums from staged K (R15-verified) ----
  float sums[2][4] = {{0.f, 0.f, 0.f, 0.f}, {0.f, 0.f, 0.f, 0.f}};
  stage_k(0, 0);
  for (int kt = 0; kt < 32; ++kt) {
    const int cur = kt & 1;
    asm volatile("s_waitcnt vmcnt(0)" ::: "memory");   // own stage(kt) landed
    __builtin_amdgcn_sched_barrier(0);
    __builtin_amdgcn_s_barrier();                      // all waves' stage landed
    bf16x8 bk8[4][2];
#pragma unroll
    for (int st = 0; st < 4; ++st)
#pragma unroll
      for (int d = 0; d < 2; ++d) {
        const int row = st * 16 + lr;
        bk8[st][d] = *reinterpret_cast<const bf16x8*>(
            &Ks[cur][(((row << 3) | ((d * 4 + lg) ^ (row & 7)))) << 3]);
      }
    if (kt + 1 < 32) stage_k(kt + 1, cur ^ 1);         // flies under compute
    const int kc = kt * 64;
    const bool okt = tokb[kt] != 0;
#pragma unroll
    for (int g = 0; g < 2; ++g)
#pragma unroll
      for (int st = 0; st < 4; ++st) {
        f32x4 s = {0.f, 0.f, 0.f, 0.f};
        s = mfma16(aq[g][0], bk8[st][0], s);
        s = mfma16(aq[g][1], bk8[st][1], s);
#pragma unroll
        for (int r = 0; r < 4; ++r) {
          float sc = s[r];
          if (!okt) {
            const int qrow = q0 + g * 16 + lg * 4 + r;
            const int kpos = kc + st * 16 + lr;
            const u32 wb = bitsb[(size_t)qrow * 64 + (kpos >> 5)];
            if (!((wb >> (kpos & 31)) & 1u)) sc = -1e30f;
          }
          sums[g][r] += __builtin_amdgcn_exp2f(sc);
        }
      }
  }
  float rinv[2][4];
#pragma unroll
  for (int g = 0; g < 2; ++g)
#pragma unroll
    for (int r = 0; r < 4; ++r) {
      float vsum = sums[g][r];
      vsum += __shfl_xor(vsum, 1);
      vsum += __shfl_xor(vsum, 2);
      vsum += __shfl_xor(vsum, 4);
      vsum += __shfl_xor(vsum, 8);
      rinv[g][r] = 1.0f / vsum;
    }
  __syncthreads();                                     // pass1/pass2 phase split

  // ---- pass 2: staged K+V, counted-vmcnt pipeline, nt stores never drained ----
  f32x4 cacc[2][4] = {};
  stage_k(0, 0);
  stage_v(0, 0);
  for (int kt = 0; kt < 32; ++kt) {
    const int cur = kt & 1;
    if (kt == 0) {
      asm volatile("s_waitcnt vmcnt(0)" ::: "memory"); // only stage(0) outstanding
    } else {
      asm volatile("s_waitcnt vmcnt(8)" ::: "memory"); // retire stage(kt); keep
    }                                                  // stores(kt-1) in flight
    __builtin_amdgcn_sched_barrier(0);
    __builtin_amdgcn_s_barrier();                      // stages landed; buf^1 free
    if (kt + 1 < 32) {                                 // prefetch next tile
      stage_k(kt + 1, cur ^ 1);
      stage_v(kt + 1, cur ^ 1);
    }
    // K fragments from Ks[cur]
    bf16x8 bk8[4][2];
#pragma unroll
    for (int st = 0; st < 4; ++st)
#pragma unroll
      for (int d = 0; d < 2; ++d) {
        const int row = st * 16 + lr;
        bk8[st][d] = *reinterpret_cast<const bf16x8*>(
            &Ks[cur][(((row << 3) | ((d * 4 + lg) ^ (row & 7)))) << 3]);
      }
    const int kc = kt * 64;
    const bool okt = tokb[kt] != 0;
#pragma unroll
    for (int g = 0; g < 2; ++g)
#pragma unroll
      for (int st = 0; st < 4; ++st) {
        f32x4 s = {0.f, 0.f, 0.f, 0.f};
        s = mfma16(aq[g][0], bk8[st][0], s);
        s = mfma16(aq[g][1], bk8[st][1], s);
#pragma unroll
        for (int r = 0; r < 4; ++r) {
          float sc = s[r];
          if (!okt) {
            const int qrow = q0 + g * 16 + lg * 4 + r;
            const int kpos = kc + st * 16 + lr;
            const u32 wb = bitsb[(size_t)qrow * 64 + (kpos >> 5)];
            if (!((wb >> (kpos & 31)) & 1u)) sc = -1e30f;
          }
          const float pn = __builtin_amdgcn_exp2f(sc) * rinv[g][r];
          const int row = g * 16 + lg * 4 + r;
          const int col = st * 16 + lr;
          pbuf[wid][row][col ^ ((row & 7) << 3)] = f2bf(pn);
        }
      }
    // V fragments from Vs[cur]
    bf16x8 vf[4][2];
#pragma unroll
    for (int ds = 0; ds < 4; ++ds)
#pragma unroll
      for (int x = 0; x < 2; ++x) {
        const int row = ds * 16 + lr;
        vf[ds][x] = *reinterpret_cast<const bf16x8*>(
            &Vs[cur][(((row << 3) | ((x * 4 + lg) ^ (row & 7)))) << 3]);
      }
    // PV: wave-local pbuf readback as A-fragments (normalized bf16)
#pragma unroll
    for (int g = 0; g < 2; ++g)
#pragma unroll
      for (int ks = 0; ks < 2; ++ks) {
        const int prow = g * 16 + lr;
        const int cb = ks * 32 + lg * 8;
        const bf16x8 pa = *reinterpret_cast<const bf16x8*>(
            &pbuf[wid][prow][cb ^ ((prow & 7) << 3)]);
#pragma unroll
        for (int ds = 0; ds < 4; ++ds)
          cacc[g][ds] = mfma16(pa, vf[ds][ks], cacc[g][ds]);
      }
    // vectorized nt attn stores: 8 instrs x 1KB; rows i*4+lg, cols (l&15)*4
#pragma unroll
    for (int i = 0; i < 8; ++i) {
      const int row = i * 4 + lg;
      const int c4 = (l & 15) * 4;
      const u16x4 raw = *reinterpret_cast<const u16x4*>(
          &pbuf[wid][row][c4 ^ ((row & 7) << 3)]);
      f32x4 o;
      o[0] = bf2f(raw[0]); o[1] = bf2f(raw[1]);
      o[2] = bf2f(raw[2]); o[3] = bf2f(raw[3]);
      __builtin_nontemporal_store(
          o, reinterpret_cast<f32x4*>(attb + (size_t)(q0 + row) * SEQ + kc + c4));
    }
  }

  // ctx write: rows q0 + g*16 + lg*4 + r, d-col ds*16+lr
#pragma unroll
  for (int g = 0; g < 2; ++g)
#pragma unroll
    for (int ds = 0; ds < 4; ++ds)
#pragma unroll
      for (int r = 0; r < 4; ++r)
        ctxb[((size_t)b * SEQ + q0 + g * 16 + lg * 4 + r) * EMB + h * HDIM + ds * 16 + lr] =
            f2bf(cacc[g][ds][r]);
}

// ---------------- host launch ----------------
extern "C" void kernel_launch(void* const* d_in, const int* in_sizes, int n_in,
                              void* d_out, int out_size, void* d_ws, size_t ws_size,
                              hipStream_t stream) {
  const float* q   = (const float*)d_in[0];
  const float* k   = (const float*)d_in[1];
  const float* v   = (const float*)d_in[2];
  const int* mask  = (const int*)d_in[3];
  const float* Wk  = (const float*)d_in[4];
  const float* bk  = (const float*)d_in[5];
  const float* Wv  = (const float*)d_in[6];
  const float* bv  = (const float*)d_in[7];
  const float* Wo  = (const float*)d_in[8];
  const float* bo  = (const float*)d_in[9];

  float* outF = (float*)d_out;
  float* attnF = outF + (size_t)NB * SEQ * EMB;

  const size_t MiB = 1024 * 1024;
  char* ws = (char*)d_ws;
  u16* qb   = (u16*)(ws + 0 * MiB);
  u16* kb   = (u16*)(ws + 16 * MiB);
  u16* vb   = (u16*)(ws + 32 * MiB);
  u16* Wvb  = (u16*)(ws + 48 * MiB);
  u16* Wkb  = (u16*)(ws + 50 * MiB);
  u16* Wob  = (u16*)(ws + 52 * MiB);
  u16* qpB  = (u16*)(ws + 54 * MiB);
  u16* kpB  = (u16*)(ws + 70 * MiB);
  u16* vpT  = (u16*)(ws + 86 * MiB);
  u16* ctxb = (u16*)(ws + 102 * MiB);
  u32* bits = (u32*)(ws + 118 * MiB);
  unsigned char* tok = (unsigned char*)(ws + 120 * MiB);

  prep_kernel<<<dim3(NB * SEQ * EMB / 8 / 256, 7), 256, 0, stream>>>(
      q, k, v, Wk, Wv, Wo, mask, qb, kb, vb, Wkb, Wvb, Wob, bits);

  tileok_kernel<<<NB * 32 * 32 / 256, 256, 0, stream>>>(bits, tok);

  proj_gemm<<<dim3(EMB / 128, NB * SEQ / 128, 3), 256, 0, stream>>>(
      qb, kb, vb, Wvb, Wkb, bv, bk, qpB, kpB, vpT);

  attn_kernel<<<1024, 256, 0, stream>>>(
      qpB, kpB, vpT, bits, tok, attnF, ctxb);

  out_gemm<<<dim3(EMB / 128, NB * SEQ / 128), 256, 0, stream>>>(ctxb, Wob, bo, outF);
}